// Round 1
// baseline (14016.515 us; speedup 1.0000x reference)
//
#include <hip/hip_runtime.h>

// LSTM decoder, persistent-kernel design.
// 2 batch-groups x (64 gate WGs + 32 logit WGs) = 192 WGs, 256 thr each.
// Per step: gates = Whh@h(hi+lo) + embed_gather + b -> pointwise -> h split hi/lo ->
// flag release; logit WGs compute fc@h for the previous h in the same phase.

#define TT 256
#define NH 1024
#define NV 1000
#define WROW 2024   // V + H
#define NGROUP 2
#define GB 32       // batch per group
#define NGATE 64    // gate WGs per group (DU=16 units each)
#define NLOGIT 32
#define NWGG 96
#define DU 16

typedef __attribute__((ext_vector_type(8))) short short8;
typedef __attribute__((ext_vector_type(4))) float f32x4;

__device__ __forceinline__ unsigned short f2bf(float f) {
    unsigned int u = __float_as_uint(f);
    u += 0x7fffu + ((u >> 16) & 1u);
    return (unsigned short)(u >> 16);
}
__device__ __forceinline__ float bf2f(unsigned short s) {
    return __uint_as_float(((unsigned int)s) << 16);
}
__device__ __forceinline__ float sigm(float x) {
    return __builtin_amdgcn_rcpf(1.0f + __expf(-x));
}
__device__ __forceinline__ float tanh_f(float x) {
    return 2.0f * __builtin_amdgcn_rcpf(1.0f + __expf(-2.0f * x)) - 1.0f;
}

// ---- one-time conversion: Whh -> bf16 [4096][1024], fc_w -> bf16 [1000][1024],
// ---- enc_h -> hi/lo bf16 into h buffer slot 1.
__global__ void convert_kernel(const float* __restrict__ enc_h,
                               const float* __restrict__ Ww,
                               const float* __restrict__ fcw_f,
                               unsigned short* __restrict__ whh,
                               unsigned short* __restrict__ fcw,
                               unsigned short* __restrict__ hb) {
    const size_t NTOT = 4194304 + 1024000 + 65536;
    for (size_t idx = (size_t)blockIdx.x * blockDim.x + threadIdx.x; idx < NTOT;
         idx += (size_t)gridDim.x * blockDim.x) {
        if (idx < 4194304) {
            size_t r = idx >> 10, k = idx & 1023;
            whh[idx] = f2bf(Ww[r * WROW + 1000 + k]);
        } else if (idx < 5218304) {
            size_t j = idx - 4194304;
            fcw[j] = f2bf(fcw_f[j]);
        } else {
            size_t j = idx - 5218304;  // 0..65535 over [B=64][H=1024]
            int b = (int)(j >> 10), k = (int)(j & 1023);
            int g = b >> 5, bl = b & 31;
            float v = enc_h[j];
            unsigned short hi = f2bf(v);
            unsigned short lo = f2bf(v - bf2f(hi));
            size_t base = (((size_t)g * 2 + 1) * 2) << 15;  // [g][buf=1][hl=0]
            hb[base + (size_t)bl * NH + k] = hi;
            hb[base + (1u << 15) + (size_t)bl * NH + k] = lo;
        }
    }
}

__global__ void __launch_bounds__(256, 1)
lstm_kernel(const float* __restrict__ enc_c,
            const int* __restrict__ trg,
            const float* __restrict__ Ww,
            const float* __restrict__ Wb,
            const float* __restrict__ fcb,
            const unsigned short* __restrict__ whh,
            const unsigned short* __restrict__ fcw,
            unsigned short* __restrict__ hb,
            int* __restrict__ flags,
            float* __restrict__ out) {
    __shared__ unsigned short smw[65536];  // 128 KB: weight slice (XOR-swizzled rows)
    __shared__ float gl[4][16][33];        // gate pre-acts [gate][unit][batch(+pad)]
    __shared__ float cst[32][16];          // cell state fp32 [batch][unit]

    const int wg = blockIdx.x;
    const int g = wg / NWGG;
    const int iw = wg % NWGG;
    const int tid = threadIdx.x;
    const int wave = tid >> 6;
    const int lane = tid & 63;
    const int ml = lane & 15;
    const int kl8 = (lane >> 4) * 8;
    const int rq = (lane >> 4) * 4;
    const int gB = g * GB;
    int* gfl = flags + g * NWGG * 16;

    auto hbp = [&](int buf, int hl) -> unsigned short* {
        return hb + ((((size_t)g * 2 + buf) * 2 + hl) << 15);
    };
    auto gwait = [&](int p) {
        if (tid < 64) {
            int* f1 = gfl + tid * 16;
            int* f2 = gfl + (64 + (tid & 31)) * 16;
            for (;;) {
                int a = __hip_atomic_load(f1, __ATOMIC_RELAXED, __HIP_MEMORY_SCOPE_AGENT);
                int b = __hip_atomic_load(f2, __ATOMIC_RELAXED, __HIP_MEMORY_SCOPE_AGENT);
                if (__all((a >= p) && (b >= p))) break;
            }
        }
        __syncthreads();
        __threadfence();  // acquire: invalidate L2 so fresh h is visible (LDS weights immune)
    };
    auto garrive = [&](int val) {
        __threadfence();  // release: flush h stores to coherence point
        __syncthreads();
        if (tid == 0)
            __hip_atomic_store(gfl + iw * 16, val, __ATOMIC_RELEASE,
                               __HIP_MEMORY_SCOPE_AGENT);
    };

    if (iw < NGATE) {
        // ---------------- gate WG: owns hidden units [u0, u0+16) ----------------
        const int u0 = iw * DU;
        for (int c = tid; c < 8192; c += 256) {  // 64 rows x 2KB -> LDS (swizzled)
            int row = c >> 7, col = c & 127;
            int grow = (row >> 4) * NH + u0 + (row & 15);  // [i;f;g;o] row blocks
            short8 v = *(const short8*)(whh + (size_t)grow * NH + col * 8);
            int byt = (col * 16) ^ ((row & 7) << 4);
            *(short8*)(smw + row * 1024 + (byt >> 1)) = v;
        }
        const int b0 = tid >> 4, uo = tid & 15;  // cells (b0,uo) and (b0+16,uo)
        float bias[4];
        #pragma unroll
        for (int q = 0; q < 4; ++q) bias[q] = Wb[q * NH + u0 + uo];
        cst[b0][uo] = enc_c[(size_t)(gB + b0) * NH + u0 + uo];
        cst[b0 + 16][uo] = enc_c[(size_t)(gB + b0 + 16) * NH + u0 + uo];
        __syncthreads();
        const int arow = wave * DU + ml;  // wave == gate type
        for (int p = 0; p < TT; ++p) {
            // embed gather prefetch (independent of other WGs -> overlaps barrier)
            int i0 = trg[(gB + b0) * TT + p];
            int i1 = trg[(gB + b0 + 16) * TT + p];
            float e0[4], e1[4];
            #pragma unroll
            for (int q = 0; q < 4; ++q) {
                e0[q] = Ww[(size_t)(q * NH + u0 + uo) * WROW + i0];
                e1[q] = Ww[(size_t)(q * NH + u0 + uo) * WROW + i1];
            }
            if (p) gwait(p);
            const unsigned short* hh = hbp((p & 1) ^ 1, 0);
            const unsigned short* hl = hbp((p & 1) ^ 1, 1);
            const short8* p0h = (const short8*)(hh + (size_t)ml * NH + kl8);
            const short8* p1h = (const short8*)(hh + (size_t)(16 + ml) * NH + kl8);
            const short8* p0l = (const short8*)(hl + (size_t)ml * NH + kl8);
            const short8* p1l = (const short8*)(hl + (size_t)(16 + ml) * NH + kl8);
            f32x4 c0h = {0,0,0,0}, c0l = {0,0,0,0}, c1h = {0,0,0,0}, c1l = {0,0,0,0};
            #pragma unroll 4
            for (int kt = 0; kt < 32; ++kt) {
                int byt = ((kt * 32 + kl8) * 2) ^ ((arow & 7) << 4);
                short8 a = *(const short8*)(smw + arow * 1024 + (byt >> 1));
                c0h = __builtin_amdgcn_mfma_f32_16x16x32_bf16(a, p0h[kt * 4], c0h, 0, 0, 0);
                c0l = __builtin_amdgcn_mfma_f32_16x16x32_bf16(a, p0l[kt * 4], c0l, 0, 0, 0);
                c1h = __builtin_amdgcn_mfma_f32_16x16x32_bf16(a, p1h[kt * 4], c1h, 0, 0, 0);
                c1l = __builtin_amdgcn_mfma_f32_16x16x32_bf16(a, p1l[kt * 4], c1l, 0, 0, 0);
            }
            f32x4 A0 = c0h + c0l, A1 = c1h + c1l;
            #pragma unroll
            for (int r = 0; r < 4; ++r) {
                gl[wave][rq + r][ml] = A0[r];
                gl[wave][rq + r][16 + ml] = A1[r];
            }
            __syncthreads();
            unsigned short* nhh = hbp(p & 1, 0);
            unsigned short* nhl = hbp(p & 1, 1);
            #pragma unroll
            for (int h2 = 0; h2 < 2; ++h2) {
                int b = b0 + h2 * 16;
                const float* e = h2 ? e1 : e0;
                float pi = gl[0][uo][b] + e[0] + bias[0];
                float pf = gl[1][uo][b] + e[1] + bias[1];
                float pg = gl[2][uo][b] + e[2] + bias[2];
                float po = gl[3][uo][b] + e[3] + bias[3];
                float ii = sigm(pi), ff = sigm(pf), gg = tanh_f(pg), oo = sigm(po);
                float cc = ff * cst[b][uo] + ii * gg;
                cst[b][uo] = cc;
                float hv = oo * tanh_f(cc);
                unsigned short hiv = f2bf(hv);
                nhh[(size_t)b * NH + u0 + uo] = hiv;
                nhl[(size_t)b * NH + u0 + uo] = f2bf(hv - bf2f(hiv));
            }
            garrive(p + 1);
        }
    } else {
        // ---------------- logit WG: owns vocab rows [v0, v0+32) ----------------
        const int lw = iw - NGATE;
        const int v0 = lw * 32;
        const int mt = wave >> 1, nt = wave & 1;
        for (int c = tid; c < 4096; c += 256) {  // 32 rows x 2KB -> LDS
            int row = c >> 7, col = c & 127;
            int grow = v0 + row;
            if (grow > NV - 1) grow = NV - 1;
            short8 v = *(const short8*)(fcw + (size_t)grow * NH + col * 8);
            int byt = (col * 16) ^ ((row & 7) << 4);
            *(short8*)(smw + row * 1024 + (byt >> 1)) = v;
        }
        int vr[4];
        float fb[4];
        #pragma unroll
        for (int r = 0; r < 4; ++r) {
            int v = v0 + mt * 16 + rq + r;
            vr[r] = v;
            fb[r] = fcb[v < NV ? v : NV - 1];
        }
        __syncthreads();
        if (tid == 0)
            __hip_atomic_store(gfl + iw * 16, 1, __ATOMIC_RELEASE,
                               __HIP_MEMORY_SCOPE_AGENT);
        const int arow = mt * 16 + ml;
        const int bloc = nt * 16 + ml;
        for (int p = 1; p <= TT; ++p) {
            gwait(p);
            const unsigned short* hh = hbp((p & 1) ^ 1, 0);
            const unsigned short* hl = hbp((p & 1) ^ 1, 1);
            const short8* ph = (const short8*)(hh + (size_t)bloc * NH + kl8);
            const short8* pl = (const short8*)(hl + (size_t)bloc * NH + kl8);
            f32x4 ch = {0,0,0,0}, clo = {0,0,0,0};
            #pragma unroll 4
            for (int kt = 0; kt < 32; ++kt) {
                int byt = ((kt * 32 + kl8) * 2) ^ ((arow & 7) << 4);
                short8 a = *(const short8*)(smw + arow * 1024 + (byt >> 1));
                ch = __builtin_amdgcn_mfma_f32_16x16x32_bf16(a, ph[kt * 4], ch, 0, 0, 0);
                clo = __builtin_amdgcn_mfma_f32_16x16x32_bf16(a, pl[kt * 4], clo, 0, 0, 0);
            }
            f32x4 A = ch + clo;
            const size_t brow = ((size_t)(gB + bloc) * TT + (p - 1)) * NV;
            #pragma unroll
            for (int r = 0; r < 4; ++r)
                if (vr[r] < NV) out[brow + vr[r]] = A[r] + fb[r];
            if (p < TT) garrive(p + 1);
        }
    }
}

extern "C" void kernel_launch(void* const* d_in, const int* in_sizes, int n_in,
                              void* d_out, int out_size, void* d_ws, size_t ws_size,
                              hipStream_t stream) {
    const float* enc_h = (const float*)d_in[0];
    const float* enc_c = (const float*)d_in[1];
    const int* trg = (const int*)d_in[2];
    const float* Ww = (const float*)d_in[3];
    const float* Wb = (const float*)d_in[4];
    const float* fcw_f = (const float*)d_in[5];
    const float* fcb = (const float*)d_in[6];

    unsigned short* whh = (unsigned short*)d_ws;              // 4096*1024 bf16
    unsigned short* fcw = whh + (size_t)4096 * 1024;          // 1000*1024 bf16
    unsigned short* hbuf = fcw + (size_t)1000 * 1024;         // [2][2][2][32][1024] bf16
    int* flags = (int*)(hbuf + (size_t)NGROUP * 2 * 2 * GB * NH);
    float* out = (float*)d_out;

    hipMemsetAsync(flags, 0, NGROUP * NWGG * 16 * sizeof(int), stream);
    hipLaunchKernelGGL(convert_kernel, dim3(2048), dim3(256), 0, stream,
                       enc_h, Ww, fcw_f, whh, fcw, hbuf);
    hipLaunchKernelGGL(lstm_kernel, dim3(NGROUP * NWGG), dim3(256), 0, stream,
                       enc_c, trg, Ww, Wb, fcb, whh, fcw, hbuf, flags, out);
}

// Round 2
// 5419.179 us; speedup vs baseline: 2.5865x; 2.5865x over previous
//
#include <hip/hip_runtime.h>

// Persistent LSTM decoder, fence-free cross-WG pipeline.
// 64 gate WGs (16 hidden units x 4 gates each) + 16 logit WGs (64 vocab rows each).
// h exchanged hi/lo-bf16 through L3 via sc1 (agent-scope relaxed) loads/stores;
// release = s_waitcnt vmcnt(0) + relaxed atomicAdd on a single gate counter.
// Logit WGs trail on a depth-4 ring, off the gate->gate critical path.

#define TT 256
#define NH 1024
#define NV 1000
#define WROW 2024   // V + H
#define NGATE 64
#define NLOGIT 16

typedef __attribute__((ext_vector_type(8))) short short8;
typedef __attribute__((ext_vector_type(4))) float f32x4;

#define AGT __HIP_MEMORY_SCOPE_AGENT

__device__ __forceinline__ unsigned short f2bf(float f) {
    unsigned int u = __float_as_uint(f);
    u += 0x7fffu + ((u >> 16) & 1u);
    return (unsigned short)(u >> 16);
}
__device__ __forceinline__ float bf2f(unsigned short s) {
    return __uint_as_float(((unsigned int)s) << 16);
}
__device__ __forceinline__ float sigm(float x) {
    return __builtin_amdgcn_rcpf(1.0f + __expf(-x));
}
__device__ __forceinline__ float tanh_f(float x) {
    return 2.0f * __builtin_amdgcn_rcpf(1.0f + __expf(-2.0f * x)) - 1.0f;
}
// 16-B "fresh from L3" load as two 8-B agent-scope relaxed atomic loads.
__device__ __forceinline__ short8 ald16(const unsigned short* p) {
    union { unsigned long long u[2]; short8 s; } v;
    v.u[0] = __hip_atomic_load((unsigned long long*)p, __ATOMIC_RELAXED, AGT);
    v.u[1] = __hip_atomic_load((unsigned long long*)(p + 4), __ATOMIC_RELAXED, AGT);
    return v.s;
}

// ---- one-time: transpose-cast embedding block Ww[:, :V] -> embT[V][4096] bf16
__global__ void embT_kernel(const float* __restrict__ Ww, unsigned short* __restrict__ embT) {
    __shared__ unsigned short tile[64][80];
    const int rt = blockIdx.x & 63, vt = blockIdx.x >> 6;
    const int r0 = rt * 64, v0 = vt * 64;
    const int t = threadIdx.x;
    {
        int rr = t >> 2, c0 = (t & 3) * 16;
        for (int j = 0; j < 16; ++j) {
            int v = v0 + c0 + j;
            float x = (v < NV) ? Ww[(size_t)(r0 + rr) * WROW + v] : 0.f;
            tile[c0 + j][rr] = f2bf(x);
        }
    }
    __syncthreads();
    {
        int vv = t >> 2, k0 = (t & 3) * 16;
        int v = v0 + vv;
        if (v < NV)
            for (int j = 0; j < 16; ++j)
                embT[(size_t)v * 4096 + r0 + k0 + j] = tile[vv][k0 + j];
    }
}

// ---- one-time: split enc_h into hi/lo bf16 planes of ring buffer 0
__global__ void h0_kernel(const float* __restrict__ enc_h, unsigned short* __restrict__ hring) {
    int i = blockIdx.x * 256 + threadIdx.x;  // 0..65535
    float v = enc_h[i];
    unsigned short hi = f2bf(v);
    hring[i] = hi;
    hring[65536 + i] = f2bf(v - bf2f(hi));
}

__global__ void __launch_bounds__(256, 1)
lstm_kernel(const float* __restrict__ enc_c,
            const int* __restrict__ trg,
            const float* __restrict__ Ww,
            const float* __restrict__ Wb,
            const float* __restrict__ fcw,
            const float* __restrict__ fcb,
            const unsigned short* __restrict__ embT,
            unsigned short* __restrict__ hring,
            int* __restrict__ syn,
            float* __restrict__ out) {
    __shared__ unsigned short smw[65536];   // 128 KB weight slice, XOR-swizzled rows
    __shared__ float gl[4][16][68];         // pre-acts [rowtile][row-in-tile][col 0..63]
    __shared__ float cst[64][17];           // cell state fp32 [batch][unit]

    const int wg = blockIdx.x;
    const int tid = threadIdx.x;
    const int lane = tid & 63;
    const int wv = tid >> 6;
    const int kh = wv >> 1;       // k-half (0: kt 0..15, 1: kt 16..31)
    const int bth = wv & 1;       // batch half (2 MFMA col-tiles each)
    const int ml = lane & 15;
    const int kq = lane >> 4;
    const int kl8 = kq * 8;
    const int rq = kq * 4;
    int* gcnt = syn;              // gate step counter (monotone, 64 per step)
    int* lfl = syn + 32;          // 16 logit progress flags, 64 B apart

    if (wg < NGATE) {
        // ================= gate WG: hidden units [u0, u0+16), 4 gates =================
        const int u0 = wg * 16;
        for (int c = tid; c < 8192; c += 256) {   // 64 rows x 1024 bf16 -> LDS
            int row = c >> 7;
            int col8 = (c & 127) << 3;
            int grow = ((row >> 4) << 10) + u0 + (row & 15);   // q*1024 + u0 + uu
            const float* src = Ww + (size_t)grow * WROW + 1000 + col8;
            float4 a = *(const float4*)src;
            float4 b2 = *(const float4*)(src + 4);
            union { unsigned short us[8]; short8 s; } w;
            w.us[0] = f2bf(a.x); w.us[1] = f2bf(a.y); w.us[2] = f2bf(a.z); w.us[3] = f2bf(a.w);
            w.us[4] = f2bf(b2.x); w.us[5] = f2bf(b2.y); w.us[6] = f2bf(b2.z); w.us[7] = f2bf(b2.w);
            int byt = ((c & 127) << 4) ^ ((row & 7) << 4);
            *(short8*)(smw + (row << 10) + (byt >> 1)) = w.s;
        }
        const int b = tid & 63;       // pointwise role: batch
        const int q4 = tid >> 6;      // pointwise role: unit quad
        float bs[4][4];
        #pragma unroll
        for (int q = 0; q < 4; ++q)
            #pragma unroll
            for (int j = 0; j < 4; ++j)
                bs[q][j] = Wb[(q << 10) + u0 + (q4 << 2) + j];
        #pragma unroll
        for (int j = 0; j < 4; ++j)
            cst[b][(q4 << 2) + j] = enc_c[(size_t)b * NH + u0 + (q4 << 2) + j];
        __syncthreads();

        for (int p = 1; p <= TT; ++p) {
            // embedding prefetch (L2-resident; latency hides under the spin)
            int idx = trg[b * TT + p - 1];
            unsigned long long emb[4];
            #pragma unroll
            for (int q = 0; q < 4; ++q)
                emb[q] = *(const unsigned long long*)(embT + (size_t)idx * 4096 + (q << 10) + u0 + (q4 << 2));
            if (p > 1) {
                const int need = 64 * (p - 1);
                while (__hip_atomic_load(gcnt, __ATOMIC_RELAXED, AGT) < need) { }
            }
            if (p >= 5) {   // ring-reuse guard vs trailing logit WGs
                const int nf = p - 4;
                for (;;) {
                    int f = (lane < NLOGIT) ? __hip_atomic_load(lfl + lane * 16, __ATOMIC_RELAXED, AGT) : nf;
                    if (__all(f >= nf)) break;
                }
            }
            __syncthreads();

            const unsigned short* hh = hring + (size_t)((p - 1) & 3) * 131072;
            const unsigned short* hl = hh + 65536;
            f32x4 acc[4][2] = {};
            #pragma unroll
            for (int j = 0; j < 16; ++j) {
                int kb = (((kh << 4) + j) << 5) + kl8;
                short8 bh0 = ald16(hh + ((bth << 5) + ml) * NH + kb);
                short8 bl0 = ald16(hl + ((bth << 5) + ml) * NH + kb);
                short8 bh1 = ald16(hh + ((bth << 5) + 16 + ml) * NH + kb);
                short8 bl1 = ald16(hl + ((bth << 5) + 16 + ml) * NH + kb);
                #pragma unroll
                for (int rt = 0; rt < 4; ++rt) {
                    int row = (rt << 4) + ml;
                    int byt = (kb << 1) ^ ((row & 7) << 4);
                    short8 a = *(const short8*)(smw + (row << 10) + (byt >> 1));
                    acc[rt][0] = __builtin_amdgcn_mfma_f32_16x16x32_bf16(a, bh0, acc[rt][0], 0, 0, 0);
                    acc[rt][0] = __builtin_amdgcn_mfma_f32_16x16x32_bf16(a, bl0, acc[rt][0], 0, 0, 0);
                    acc[rt][1] = __builtin_amdgcn_mfma_f32_16x16x32_bf16(a, bh1, acc[rt][1], 0, 0, 0);
                    acc[rt][1] = __builtin_amdgcn_mfma_f32_16x16x32_bf16(a, bl1, acc[rt][1], 0, 0, 0);
                }
            }
            // combine the two k-halves through gl
            if (kh) {
                #pragma unroll
                for (int rt = 0; rt < 4; ++rt)
                    #pragma unroll
                    for (int i = 0; i < 2; ++i)
                        #pragma unroll
                        for (int r = 0; r < 4; ++r)
                            gl[rt][rq + r][(bth << 5) + (i << 4) + ml] = acc[rt][i][r];
            }
            __syncthreads();
            if (!kh) {
                #pragma unroll
                for (int rt = 0; rt < 4; ++rt)
                    #pragma unroll
                    for (int i = 0; i < 2; ++i)
                        #pragma unroll
                        for (int r = 0; r < 4; ++r)
                            gl[rt][rq + r][(bth << 5) + (i << 4) + ml] += acc[rt][i][r];
            }
            __syncthreads();
            // pointwise: thread handles batch b, units q4*4..+3
            unsigned long long hiw = 0, low = 0;
            #pragma unroll
            for (int j = 0; j < 4; ++j) {
                int u = (q4 << 2) + j;
                float pi = gl[0][u][b] + bs[0][j] + bf2f((unsigned short)(emb[0] >> (j * 16)));
                float pf = gl[1][u][b] + bs[1][j] + bf2f((unsigned short)(emb[1] >> (j * 16)));
                float pg = gl[2][u][b] + bs[2][j] + bf2f((unsigned short)(emb[2] >> (j * 16)));
                float po = gl[3][u][b] + bs[3][j] + bf2f((unsigned short)(emb[3] >> (j * 16)));
                float ii = sigm(pi), ff = sigm(pf), gg = tanh_f(pg), oo = sigm(po);
                float cc = ff * cst[b][u] + ii * gg;
                cst[b][u] = cc;
                float hv = oo * tanh_f(cc);
                unsigned short hb = f2bf(hv);
                hiw |= (unsigned long long)hb << (j * 16);
                low |= (unsigned long long)f2bf(hv - bf2f(hb)) << (j * 16);
            }
            unsigned short* nh = hring + (size_t)(p & 3) * 131072;
            size_t hoff = (size_t)b * NH + u0 + (q4 << 2);
            __hip_atomic_store((unsigned long long*)(nh + hoff), hiw, __ATOMIC_RELAXED, AGT);
            __hip_atomic_store((unsigned long long*)(nh + 65536 + hoff), low, __ATOMIC_RELAXED, AGT);
            asm volatile("s_waitcnt vmcnt(0)" ::: "memory");  // h stores acked before arrive
            __syncthreads();
            if (tid == 0) __hip_atomic_fetch_add(gcnt, 1, __ATOMIC_RELAXED, AGT);
        }
    } else {
        // ================= logit WG: vocab rows [v0, v0+64) =================
        const int lw = wg - NGATE;
        const int v0 = lw << 6;
        for (int c = tid; c < 8192; c += 256) {   // 64 rows of fc_w -> LDS
            int row = c >> 7;
            int col8 = (c & 127) << 3;
            int grow = v0 + row; if (grow > NV - 1) grow = NV - 1;
            const float* src = fcw + (size_t)grow * NH + col8;
            float4 a = *(const float4*)src;
            float4 b2 = *(const float4*)(src + 4);
            union { unsigned short us[8]; short8 s; } w;
            w.us[0] = f2bf(a.x); w.us[1] = f2bf(a.y); w.us[2] = f2bf(a.z); w.us[3] = f2bf(a.w);
            w.us[4] = f2bf(b2.x); w.us[5] = f2bf(b2.y); w.us[6] = f2bf(b2.z); w.us[7] = f2bf(b2.w);
            int byt = ((c & 127) << 4) ^ ((row & 7) << 4);
            *(short8*)(smw + (row << 10) + (byt >> 1)) = w.s;
        }
        f32x4 fbv[4];
        #pragma unroll
        for (int rt = 0; rt < 4; ++rt)
            #pragma unroll
            for (int r = 0; r < 4; ++r) {
                int v = v0 + (rt << 4) + rq + r;
                fbv[rt][r] = fcb[v < NV ? v : NV - 1];
            }
        __syncthreads();

        for (int q = 1; q <= TT; ++q) {
            const int need = 64 * q;
            while (__hip_atomic_load(gcnt, __ATOMIC_RELAXED, AGT) < need) { }
            __syncthreads();
            const unsigned short* hh = hring + (size_t)(q & 3) * 131072;  // hi plane only
            f32x4 acc[4][2] = {};
            #pragma unroll
            for (int j = 0; j < 16; ++j) {
                int kb = (((kh << 4) + j) << 5) + kl8;
                short8 bh0 = ald16(hh + ((bth << 5) + ml) * NH + kb);
                short8 bh1 = ald16(hh + ((bth << 5) + 16 + ml) * NH + kb);
                #pragma unroll
                for (int rt = 0; rt < 4; ++rt) {
                    int row = (rt << 4) + ml;
                    int byt = (kb << 1) ^ ((row & 7) << 4);
                    short8 a = *(const short8*)(smw + (row << 10) + (byt >> 1));
                    acc[rt][0] = __builtin_amdgcn_mfma_f32_16x16x32_bf16(a, bh0, acc[rt][0], 0, 0, 0);
                    acc[rt][1] = __builtin_amdgcn_mfma_f32_16x16x32_bf16(a, bh1, acc[rt][1], 0, 0, 0);
                }
            }
            if (kh) {
                #pragma unroll
                for (int rt = 0; rt < 4; ++rt)
                    #pragma unroll
                    for (int i = 0; i < 2; ++i)
                        #pragma unroll
                        for (int r = 0; r < 4; ++r)
                            gl[rt][rq + r][(bth << 5) + (i << 4) + ml] = acc[rt][i][r];
            }
            __syncthreads();
            if (!kh) {
                #pragma unroll
                for (int rt = 0; rt < 4; ++rt) {
                    int vq = v0 + (rt << 4) + rq;
                    #pragma unroll
                    for (int i = 0; i < 2; ++i) {
                        int bb = (bth << 5) + (i << 4) + ml;
                        f32x4 v = acc[rt][i] + fbv[rt];
                        #pragma unroll
                        for (int r = 0; r < 4; ++r) v[r] += gl[rt][rq + r][bb];
                        if (vq + 3 < NV)
                            __builtin_nontemporal_store(v, (f32x4*)(out + ((size_t)bb * TT + (q - 1)) * NV + vq));
                    }
                }
            }
            asm volatile("s_waitcnt vmcnt(0)" ::: "memory");  // h reads + out stores drained
            __syncthreads();
            if (tid == 0) __hip_atomic_store(lfl + lw * 16, q, __ATOMIC_RELAXED, AGT);
        }
    }
}

extern "C" void kernel_launch(void* const* d_in, const int* in_sizes, int n_in,
                              void* d_out, int out_size, void* d_ws, size_t ws_size,
                              hipStream_t stream) {
    const float* enc_h = (const float*)d_in[0];
    const float* enc_c = (const float*)d_in[1];
    const int* trg = (const int*)d_in[2];
    const float* Ww = (const float*)d_in[3];
    const float* Wb = (const float*)d_in[4];
    const float* fcw = (const float*)d_in[5];
    const float* fcb = (const float*)d_in[6];

    unsigned short* embT = (unsigned short*)d_ws;            // 1000 x 4096 bf16 (8 MB)
    unsigned short* hring = embT + (size_t)1000 * 4096;      // 4 bufs x [2][64][1024] bf16 (1 MB)
    int* syn = (int*)(hring + (size_t)4 * 131072);           // counter + logit flags
    float* out = (float*)d_out;

    hipMemsetAsync(syn, 0, 4096, stream);
    hipLaunchKernelGGL(embT_kernel, dim3(1024), dim3(256), 0, stream, Ww, embT);
    hipLaunchKernelGGL(h0_kernel, dim3(256), dim3(256), 0, stream, enc_h, hring);
    hipLaunchKernelGGL(lstm_kernel, dim3(NGATE + NLOGIT), dim3(256), 0, stream,
                       enc_c, trg, Ww, Wb, fcw, fcb, embT, hring, syn, out);
}

// Round 3
// 4663.595 us; speedup vs baseline: 3.0055x; 1.1620x over previous
//
#include <hip/hip_runtime.h>

// Persistent LSTM decoder, fence-free cross-WG pipeline, RMW-free sync.
// 64 gate WGs (16 hidden units x 4 gates each) + 16 logit WGs (64 vocab rows each).
// h exchanged hi/lo-bf16 through coherent L2/L3 via agent-scope relaxed atomics;
// release = s_waitcnt vmcnt(0) + per-WG epoch flag STORE (one line per WG, no RMW).
// Waiters: wave 0 only, one lane per flag. Logit WGs trail on a depth-4 ring.

#define TT 256
#define NH 1024
#define NV 1000
#define WROW 2024   // V + H
#define NGATE 64
#define NLOGIT 16

typedef __attribute__((ext_vector_type(8))) short short8;
typedef __attribute__((ext_vector_type(4))) float f32x4;

#define AGT __HIP_MEMORY_SCOPE_AGENT

__device__ __forceinline__ unsigned short f2bf(float f) {
    unsigned int u = __float_as_uint(f);
    u += 0x7fffu + ((u >> 16) & 1u);
    return (unsigned short)(u >> 16);
}
__device__ __forceinline__ float bf2f(unsigned short s) {
    return __uint_as_float(((unsigned int)s) << 16);
}
__device__ __forceinline__ float sigm(float x) {
    return __builtin_amdgcn_rcpf(1.0f + __expf(-x));
}
__device__ __forceinline__ float tanh_f(float x) {
    return 2.0f * __builtin_amdgcn_rcpf(1.0f + __expf(-2.0f * x)) - 1.0f;
}
// 16-B "fresh" load as two 8-B agent-scope relaxed atomic loads.
__device__ __forceinline__ short8 ald16(const unsigned short* p) {
    union { unsigned long long u[2]; short8 s; } v;
    v.u[0] = __hip_atomic_load((unsigned long long*)p, __ATOMIC_RELAXED, AGT);
    v.u[1] = __hip_atomic_load((unsigned long long*)(p + 4), __ATOMIC_RELAXED, AGT);
    return v.s;
}

// ---- one-time: transpose-cast embedding block Ww[:, :V] -> embT[V][4096] bf16
__global__ void embT_kernel(const float* __restrict__ Ww, unsigned short* __restrict__ embT) {
    __shared__ unsigned short tile[64][80];
    const int rt = blockIdx.x & 63, vt = blockIdx.x >> 6;
    const int r0 = rt * 64, v0 = vt * 64;
    const int t = threadIdx.x;
    {
        int rr = t >> 2, c0 = (t & 3) * 16;
        for (int j = 0; j < 16; ++j) {
            int v = v0 + c0 + j;
            float x = (v < NV) ? Ww[(size_t)(r0 + rr) * WROW + v] : 0.f;
            tile[c0 + j][rr] = f2bf(x);
        }
    }
    __syncthreads();
    {
        int vv = t >> 2, k0 = (t & 3) * 16;
        int v = v0 + vv;
        if (v < NV)
            for (int j = 0; j < 16; ++j)
                embT[(size_t)v * 4096 + r0 + k0 + j] = tile[vv][k0 + j];
    }
}

// ---- one-time: split enc_h into hi/lo bf16 planes of ring buffer 0
__global__ void h0_kernel(const float* __restrict__ enc_h, unsigned short* __restrict__ hring) {
    int i = blockIdx.x * 256 + threadIdx.x;  // 0..65535
    float v = enc_h[i];
    unsigned short hi = f2bf(v);
    hring[i] = hi;
    hring[65536 + i] = f2bf(v - bf2f(hi));
}

__global__ void __launch_bounds__(256, 1)
lstm_kernel(const float* __restrict__ enc_c,
            const int* __restrict__ trg,
            const float* __restrict__ Ww,
            const float* __restrict__ Wb,
            const float* __restrict__ fcw,
            const float* __restrict__ fcb,
            const unsigned short* __restrict__ embT,
            unsigned short* __restrict__ hring,
            int* __restrict__ syn,
            float* __restrict__ out) {
    __shared__ unsigned short smw[65536];   // 128 KB weight slice, XOR-swizzled rows
    __shared__ float gl[4][16][68];         // pre-acts [rowtile][row-in-tile][col 0..63]
    __shared__ float cst[64][17];           // cell state fp32 [batch][unit]

    const int wg = blockIdx.x;
    const int tid = threadIdx.x;
    const int lane = tid & 63;
    const int wv = tid >> 6;
    const int kh = wv >> 1;       // k-half (0: kt 0..15, 1: kt 16..31)
    const int bth = wv & 1;       // batch half (2 MFMA col-tiles each)
    const int ml = lane & 15;
    const int kq = lane >> 4;
    const int kl8 = kq * 8;
    const int rq = kq * 4;
    int* gfl = syn;               // 64 gate epoch flags, 64 B apart
    int* lfl = syn + 1024;        // 16 logit progress flags, 64 B apart

    if (wg < NGATE) {
        // ================= gate WG: hidden units [u0, u0+16), 4 gates =================
        const int u0 = wg * 16;
        for (int c = tid; c < 8192; c += 256) {   // 64 rows x 1024 bf16 -> LDS
            int row = c >> 7;
            int col8 = (c & 127) << 3;
            int grow = ((row >> 4) << 10) + u0 + (row & 15);   // q*1024 + u0 + uu
            const float* src = Ww + (size_t)grow * WROW + 1000 + col8;
            float4 a = *(const float4*)src;
            float4 b2 = *(const float4*)(src + 4);
            union { unsigned short us[8]; short8 s; } w;
            w.us[0] = f2bf(a.x); w.us[1] = f2bf(a.y); w.us[2] = f2bf(a.z); w.us[3] = f2bf(a.w);
            w.us[4] = f2bf(b2.x); w.us[5] = f2bf(b2.y); w.us[6] = f2bf(b2.z); w.us[7] = f2bf(b2.w);
            int byt = ((c & 127) << 4) ^ ((row & 7) << 4);
            *(short8*)(smw + (row << 10) + (byt >> 1)) = w.s;
        }
        const int b = tid & 63;       // pointwise role: batch
        const int q4 = tid >> 6;      // pointwise role: unit quad
        float bs[4][4];
        #pragma unroll
        for (int q = 0; q < 4; ++q)
            #pragma unroll
            for (int j = 0; j < 4; ++j)
                bs[q][j] = Wb[(q << 10) + u0 + (q4 << 2) + j];
        #pragma unroll
        for (int j = 0; j < 4; ++j)
            cst[b][(q4 << 2) + j] = enc_c[(size_t)b * NH + u0 + (q4 << 2) + j];
        __syncthreads();

        for (int p = 1; p <= TT; ++p) {
            // embedding prefetch (L2-resident; latency hides under the spin)
            int idx = trg[b * TT + p - 1];
            unsigned long long emb[4];
            #pragma unroll
            for (int q = 0; q < 4; ++q)
                emb[q] = *(const unsigned long long*)(embT + (size_t)idx * 4096 + (q << 10) + u0 + (q4 << 2));
            // wait: wave 0 only, one lane per producer flag (no RMW anywhere)
            if (tid < 64) {
                if (p > 1) {
                    int* f = gfl + tid * 16;
                    while (__hip_atomic_load(f, __ATOMIC_RELAXED, AGT) < p - 1) { }
                }
                if (p >= 5) {   // ring-reuse guard vs trailing logit WGs
                    int* f2 = lfl + (tid & 15) * 16;
                    while (__hip_atomic_load(f2, __ATOMIC_RELAXED, AGT) < p - 4) { }
                }
            }
            __syncthreads();

            const unsigned short* hh = hring + (size_t)((p - 1) & 3) * 131072;
            const unsigned short* hl = hh + 65536;
            f32x4 acc[4][2] = {};
            #pragma unroll
            for (int j = 0; j < 16; ++j) {
                int kb = (((kh << 4) + j) << 5) + kl8;
                short8 bh0 = ald16(hh + ((bth << 5) + ml) * NH + kb);
                short8 bl0 = ald16(hl + ((bth << 5) + ml) * NH + kb);
                short8 bh1 = ald16(hh + ((bth << 5) + 16 + ml) * NH + kb);
                short8 bl1 = ald16(hl + ((bth << 5) + 16 + ml) * NH + kb);
                #pragma unroll
                for (int rt = 0; rt < 4; ++rt) {
                    int row = (rt << 4) + ml;
                    int byt = (kb << 1) ^ ((row & 7) << 4);
                    short8 a = *(const short8*)(smw + (row << 10) + (byt >> 1));
                    acc[rt][0] = __builtin_amdgcn_mfma_f32_16x16x32_bf16(a, bh0, acc[rt][0], 0, 0, 0);
                    acc[rt][0] = __builtin_amdgcn_mfma_f32_16x16x32_bf16(a, bl0, acc[rt][0], 0, 0, 0);
                    acc[rt][1] = __builtin_amdgcn_mfma_f32_16x16x32_bf16(a, bh1, acc[rt][1], 0, 0, 0);
                    acc[rt][1] = __builtin_amdgcn_mfma_f32_16x16x32_bf16(a, bl1, acc[rt][1], 0, 0, 0);
                }
            }
            // combine the two k-halves through gl
            if (kh) {
                #pragma unroll
                for (int rt = 0; rt < 4; ++rt)
                    #pragma unroll
                    for (int i = 0; i < 2; ++i)
                        #pragma unroll
                        for (int r = 0; r < 4; ++r)
                            gl[rt][rq + r][(bth << 5) + (i << 4) + ml] = acc[rt][i][r];
            }
            __syncthreads();
            if (!kh) {
                #pragma unroll
                for (int rt = 0; rt < 4; ++rt)
                    #pragma unroll
                    for (int i = 0; i < 2; ++i)
                        #pragma unroll
                        for (int r = 0; r < 4; ++r)
                            gl[rt][rq + r][(bth << 5) + (i << 4) + ml] += acc[rt][i][r];
            }
            __syncthreads();
            // pointwise: thread handles batch b, units q4*4..+3
            unsigned long long hiw = 0, low = 0;
            #pragma unroll
            for (int j = 0; j < 4; ++j) {
                int u = (q4 << 2) + j;
                float pi = gl[0][u][b] + bs[0][j] + bf2f((unsigned short)(emb[0] >> (j * 16)));
                float pf = gl[1][u][b] + bs[1][j] + bf2f((unsigned short)(emb[1] >> (j * 16)));
                float pg = gl[2][u][b] + bs[2][j] + bf2f((unsigned short)(emb[2] >> (j * 16)));
                float po = gl[3][u][b] + bs[3][j] + bf2f((unsigned short)(emb[3] >> (j * 16)));
                float ii = sigm(pi), ff = sigm(pf), gg = tanh_f(pg), oo = sigm(po);
                float cc = ff * cst[b][u] + ii * gg;
                cst[b][u] = cc;
                float hv = oo * tanh_f(cc);
                unsigned short hb = f2bf(hv);
                hiw |= (unsigned long long)hb << (j * 16);
                low |= (unsigned long long)f2bf(hv - bf2f(hb)) << (j * 16);
            }
            unsigned short* nh = hring + (size_t)(p & 3) * 131072;
            size_t hoff = (size_t)b * NH + u0 + (q4 << 2);
            __hip_atomic_store((unsigned long long*)(nh + hoff), hiw, __ATOMIC_RELAXED, AGT);
            __hip_atomic_store((unsigned long long*)(nh + 65536 + hoff), low, __ATOMIC_RELAXED, AGT);
            asm volatile("s_waitcnt vmcnt(0)" ::: "memory");  // h stores acked before arrive
            __syncthreads();
            if (tid == 0)
                __hip_atomic_store(gfl + wg * 16, p, __ATOMIC_RELAXED, AGT);
        }
    } else {
        // ================= logit WG: vocab rows [v0, v0+64) =================
        const int lw = wg - NGATE;
        const int v0 = lw << 6;
        for (int c = tid; c < 8192; c += 256) {   // 64 rows of fc_w -> LDS
            int row = c >> 7;
            int col8 = (c & 127) << 3;
            int grow = v0 + row; if (grow > NV - 1) grow = NV - 1;
            const float* src = fcw + (size_t)grow * NH + col8;
            float4 a = *(const float4*)src;
            float4 b2 = *(const float4*)(src + 4);
            union { unsigned short us[8]; short8 s; } w;
            w.us[0] = f2bf(a.x); w.us[1] = f2bf(a.y); w.us[2] = f2bf(a.z); w.us[3] = f2bf(a.w);
            w.us[4] = f2bf(b2.x); w.us[5] = f2bf(b2.y); w.us[6] = f2bf(b2.z); w.us[7] = f2bf(b2.w);
            int byt = ((c & 127) << 4) ^ ((row & 7) << 4);
            *(short8*)(smw + (row << 10) + (byt >> 1)) = w.s;
        }
        f32x4 fbv[4];
        #pragma unroll
        for (int rt = 0; rt < 4; ++rt)
            #pragma unroll
            for (int r = 0; r < 4; ++r) {
                int v = v0 + (rt << 4) + rq + r;
                fbv[rt][r] = fcb[v < NV ? v : NV - 1];
            }
        __syncthreads();

        for (int q = 1; q <= TT; ++q) {
            if (tid < 64) {
                int* f = gfl + tid * 16;
                while (__hip_atomic_load(f, __ATOMIC_RELAXED, AGT) < q) { }
            }
            __syncthreads();
            const unsigned short* hh = hring + (size_t)(q & 3) * 131072;  // hi plane only
            f32x4 acc[4][2] = {};
            #pragma unroll
            for (int j = 0; j < 16; ++j) {
                int kb = (((kh << 4) + j) << 5) + kl8;
                short8 bh0 = ald16(hh + ((bth << 5) + ml) * NH + kb);
                short8 bh1 = ald16(hh + ((bth << 5) + 16 + ml) * NH + kb);
                #pragma unroll
                for (int rt = 0; rt < 4; ++rt) {
                    int row = (rt << 4) + ml;
                    int byt = (kb << 1) ^ ((row & 7) << 4);
                    short8 a = *(const short8*)(smw + (row << 10) + (byt >> 1));
                    acc[rt][0] = __builtin_amdgcn_mfma_f32_16x16x32_bf16(a, bh0, acc[rt][0], 0, 0, 0);
                    acc[rt][1] = __builtin_amdgcn_mfma_f32_16x16x32_bf16(a, bh1, acc[rt][1], 0, 0, 0);
                }
            }
            if (kh) {
                #pragma unroll
                for (int rt = 0; rt < 4; ++rt)
                    #pragma unroll
                    for (int i = 0; i < 2; ++i)
                        #pragma unroll
                        for (int r = 0; r < 4; ++r)
                            gl[rt][rq + r][(bth << 5) + (i << 4) + ml] = acc[rt][i][r];
            }
            __syncthreads();
            if (!kh) {
                #pragma unroll
                for (int rt = 0; rt < 4; ++rt) {
                    int vq = v0 + (rt << 4) + rq;
                    #pragma unroll
                    for (int i = 0; i < 2; ++i) {
                        int bb = (bth << 5) + (i << 4) + ml;
                        f32x4 v = acc[rt][i] + fbv[rt];
                        #pragma unroll
                        for (int r = 0; r < 4; ++r) v[r] += gl[rt][rq + r][bb];
                        if (vq + 3 < NV)
                            __builtin_nontemporal_store(v, (f32x4*)(out + ((size_t)bb * TT + (q - 1)) * NV + vq));
                    }
                }
            }
            asm volatile("s_waitcnt vmcnt(0)" ::: "memory");  // h reads + out stores drained
            __syncthreads();
            if (tid == 0)
                __hip_atomic_store(lfl + lw * 16, q, __ATOMIC_RELAXED, AGT);
        }
    }
}

extern "C" void kernel_launch(void* const* d_in, const int* in_sizes, int n_in,
                              void* d_out, int out_size, void* d_ws, size_t ws_size,
                              hipStream_t stream) {
    const float* enc_h = (const float*)d_in[0];
    const float* enc_c = (const float*)d_in[1];
    const int* trg = (const int*)d_in[2];
    const float* Ww = (const float*)d_in[3];
    const float* Wb = (const float*)d_in[4];
    const float* fcw = (const float*)d_in[5];
    const float* fcb = (const float*)d_in[6];

    unsigned short* embT = (unsigned short*)d_ws;            // 1000 x 4096 bf16 (8 MB)
    unsigned short* hring = embT + (size_t)1000 * 4096;      // 4 bufs x [2][64][1024] bf16 (1 MB)
    int* syn = (int*)(hring + (size_t)4 * 131072);           // 64 gate flags + 16 logit flags
    float* out = (float*)d_out;

    hipMemsetAsync(syn, 0, 8192, stream);
    hipLaunchKernelGGL(embT_kernel, dim3(1024), dim3(256), 0, stream, Ww, embT);
    hipLaunchKernelGGL(h0_kernel, dim3(256), dim3(256), 0, stream, enc_h, hring);
    hipLaunchKernelGGL(lstm_kernel, dim3(NGATE + NLOGIT), dim3(256), 0, stream,
                       enc_c, trg, Ww, Wb, fcw, fcb, embT, hring, syn, out);
}

// Round 4
// 3447.883 us; speedup vs baseline: 4.0653x; 1.3526x over previous
//
#include <hip/hip_runtime.h>

// Persistent LSTM decoder, fence-free-release / acquire-inv pipeline.
// 64 gate WGs (16 hidden units x 4 gates each) + 16 logit WGs (64 vocab rows each).
// h written hi/lo-bf16 via sc1 write-through stores (vmcnt(0)-acked before flag);
// consumers do ONE agent acquire fence (buffer_inv) per step, then PLAIN cached
// loads -> h broadcast is served from each XCD's L2 instead of hammering L3.
// Logit WGs trail on a depth-4 ring, off the gate->gate critical path.

#define TT 256
#define NH 1024
#define NV 1000
#define WROW 2024   // V + H
#define NGATE 64
#define NLOGIT 16

typedef __attribute__((ext_vector_type(8))) short short8;
typedef __attribute__((ext_vector_type(4))) float f32x4;

#define AGT __HIP_MEMORY_SCOPE_AGENT

__device__ __forceinline__ unsigned short f2bf(float f) {
    unsigned int u = __float_as_uint(f);
    u += 0x7fffu + ((u >> 16) & 1u);
    return (unsigned short)(u >> 16);
}
__device__ __forceinline__ float bf2f(unsigned short s) {
    return __uint_as_float(((unsigned int)s) << 16);
}
__device__ __forceinline__ float sigm(float x) {
    return __builtin_amdgcn_rcpf(1.0f + __expf(-x));
}
__device__ __forceinline__ float tanh_f(float x) {
    return 2.0f * __builtin_amdgcn_rcpf(1.0f + __expf(-2.0f * x)) - 1.0f;
}

// ---- one-time: transpose-cast embedding block Ww[:, :V] -> embT[V][4096] bf16
__global__ void embT_kernel(const float* __restrict__ Ww, unsigned short* __restrict__ embT) {
    __shared__ unsigned short tile[64][80];
    const int rt = blockIdx.x & 63, vt = blockIdx.x >> 6;
    const int r0 = rt * 64, v0 = vt * 64;
    const int t = threadIdx.x;
    {
        int rr = t >> 2, c0 = (t & 3) * 16;
        for (int j = 0; j < 16; ++j) {
            int v = v0 + c0 + j;
            float x = (v < NV) ? Ww[(size_t)(r0 + rr) * WROW + v] : 0.f;
            tile[c0 + j][rr] = f2bf(x);
        }
    }
    __syncthreads();
    {
        int vv = t >> 2, k0 = (t & 3) * 16;
        int v = v0 + vv;
        if (v < NV)
            for (int j = 0; j < 16; ++j)
                embT[(size_t)v * 4096 + r0 + k0 + j] = tile[vv][k0 + j];
    }
}

// ---- one-time: split enc_h into hi/lo bf16 planes of ring buffer 0
__global__ void h0_kernel(const float* __restrict__ enc_h, unsigned short* __restrict__ hring) {
    int i = blockIdx.x * 256 + threadIdx.x;  // 0..65535
    float v = enc_h[i];
    unsigned short hi = f2bf(v);
    hring[i] = hi;
    hring[65536 + i] = f2bf(v - bf2f(hi));
}

__global__ void __launch_bounds__(256, 1)
lstm_kernel(const float* __restrict__ enc_c,
            const int* __restrict__ trg,
            const float* __restrict__ Ww,
            const float* __restrict__ Wb,
            const float* __restrict__ fcw,
            const float* __restrict__ fcb,
            const unsigned short* __restrict__ embT,
            unsigned short* __restrict__ hring,
            int* __restrict__ syn,
            float* __restrict__ out) {
    __shared__ unsigned short smw[65536];   // 128 KB: weight slice, XOR-swizzled rows
    __shared__ float gl[4][16][68];         // pre-acts [rowtile][row-in-tile][col 0..63]
    __shared__ float cst[64][17];           // cell state fp32 [batch][unit]

    const int wg = blockIdx.x;
    const int tid = threadIdx.x;
    const int lane = tid & 63;
    const int wv = tid >> 6;
    const int kh = wv >> 1;       // k-half (0: kt 0..15, 1: kt 16..31)
    const int bth = wv & 1;       // batch half (2 MFMA col-tiles each)
    const int ml = lane & 15;
    const int kq = lane >> 4;
    const int kl8 = kq * 8;
    const int rq = kq * 4;
    int* gfl = syn;               // 64 gate epoch flags, 64 B apart
    int* lfl = syn + 1024;        // 16 logit progress flags, 64 B apart

    if (wg < NGATE) {
        // ================= gate WG: hidden units [u0, u0+16), 4 gates =================
        const int u0 = wg * 16;
        for (int c = tid; c < 8192; c += 256) {   // 64 rows x 1024 bf16 -> LDS
            int row = c >> 7;
            int col8 = (c & 127) << 3;
            int grow = ((row >> 4) << 10) + u0 + (row & 15);   // q*1024 + u0 + uu
            const float* src = Ww + (size_t)grow * WROW + 1000 + col8;
            float4 a = *(const float4*)src;
            float4 b2 = *(const float4*)(src + 4);
            union { unsigned short us[8]; short8 s; } w;
            w.us[0] = f2bf(a.x); w.us[1] = f2bf(a.y); w.us[2] = f2bf(a.z); w.us[3] = f2bf(a.w);
            w.us[4] = f2bf(b2.x); w.us[5] = f2bf(b2.y); w.us[6] = f2bf(b2.z); w.us[7] = f2bf(b2.w);
            int byt = ((c & 127) << 4) ^ ((row & 7) << 4);
            *(short8*)(smw + (row << 10) + (byt >> 1)) = w.s;
        }
        const int b = tid & 63;       // pointwise role: batch
        const int q4 = tid >> 6;      // pointwise role: unit quad
        float bs[4][4];
        #pragma unroll
        for (int q = 0; q < 4; ++q)
            #pragma unroll
            for (int j = 0; j < 4; ++j)
                bs[q][j] = Wb[(q << 10) + u0 + (q4 << 2) + j];
        #pragma unroll
        for (int j = 0; j < 4; ++j)
            cst[b][(q4 << 2) + j] = enc_c[(size_t)b * NH + u0 + (q4 << 2) + j];
        __syncthreads();

        for (int p = 1; p <= TT; ++p) {
            // embedding prefetch (plain cached loads; land before the fence's waitcnt)
            int idx = trg[b * TT + p - 1];
            unsigned long long emb[4];
            #pragma unroll
            for (int q = 0; q < 4; ++q)
                emb[q] = *(const unsigned long long*)(embT + (size_t)idx * 4096 + (q << 10) + u0 + (q4 << 2));
            // wait: wave 0 only, one lane per producer flag (sc1 polls, no RMW)
            if (tid < 64) {
                if (p > 1) {
                    int* f = gfl + tid * 16;
                    while (__hip_atomic_load(f, __ATOMIC_RELAXED, AGT) < p - 1) { }
                }
                if (p >= 5) {   // ring-reuse guard vs trailing logit WGs
                    int* f2 = lfl + (tid & 15) * 16;
                    while (__hip_atomic_load(f2, __ATOMIC_RELAXED, AGT) < p - 4) { }
                }
            }
            __syncthreads();
            // acquire: invalidate stale L0/L1/L2 copies, then read h via PLAIN loads
            __builtin_amdgcn_fence(__ATOMIC_ACQUIRE, "agent");

            const unsigned short* hh = hring + (size_t)((p - 1) & 3) * 131072;
            const unsigned short* hl = hh + 65536;
            f32x4 acc[4][2] = {};
            #pragma unroll
            for (int j = 0; j < 16; ++j) {
                int kb = (((kh << 4) + j) << 5) + kl8;
                short8 bh0 = *(const short8*)(hh + ((bth << 5) + ml) * NH + kb);
                short8 bl0 = *(const short8*)(hl + ((bth << 5) + ml) * NH + kb);
                short8 bh1 = *(const short8*)(hh + ((bth << 5) + 16 + ml) * NH + kb);
                short8 bl1 = *(const short8*)(hl + ((bth << 5) + 16 + ml) * NH + kb);
                #pragma unroll
                for (int rt = 0; rt < 4; ++rt) {
                    int row = (rt << 4) + ml;
                    int byt = (kb << 1) ^ ((row & 7) << 4);
                    short8 a = *(const short8*)(smw + (row << 10) + (byt >> 1));
                    acc[rt][0] = __builtin_amdgcn_mfma_f32_16x16x32_bf16(a, bh0, acc[rt][0], 0, 0, 0);
                    acc[rt][0] = __builtin_amdgcn_mfma_f32_16x16x32_bf16(a, bl0, acc[rt][0], 0, 0, 0);
                    acc[rt][1] = __builtin_amdgcn_mfma_f32_16x16x32_bf16(a, bh1, acc[rt][1], 0, 0, 0);
                    acc[rt][1] = __builtin_amdgcn_mfma_f32_16x16x32_bf16(a, bl1, acc[rt][1], 0, 0, 0);
                }
            }
            // combine the two k-halves through gl
            if (kh) {
                #pragma unroll
                for (int rt = 0; rt < 4; ++rt)
                    #pragma unroll
                    for (int i = 0; i < 2; ++i)
                        #pragma unroll
                        for (int r = 0; r < 4; ++r)
                            gl[rt][rq + r][(bth << 5) + (i << 4) + ml] = acc[rt][i][r];
            }
            __syncthreads();
            if (!kh) {
                #pragma unroll
                for (int rt = 0; rt < 4; ++rt)
                    #pragma unroll
                    for (int i = 0; i < 2; ++i)
                        #pragma unroll
                        for (int r = 0; r < 4; ++r)
                            gl[rt][rq + r][(bth << 5) + (i << 4) + ml] += acc[rt][i][r];
            }
            __syncthreads();
            // pointwise: thread handles batch b, units q4*4..+3
            unsigned long long hiw = 0, low = 0;
            #pragma unroll
            for (int j = 0; j < 4; ++j) {
                int u = (q4 << 2) + j;
                float pi = gl[0][u][b] + bs[0][j] + bf2f((unsigned short)(emb[0] >> (j * 16)));
                float pf = gl[1][u][b] + bs[1][j] + bf2f((unsigned short)(emb[1] >> (j * 16)));
                float pg = gl[2][u][b] + bs[2][j] + bf2f((unsigned short)(emb[2] >> (j * 16)));
                float po = gl[3][u][b] + bs[3][j] + bf2f((unsigned short)(emb[3] >> (j * 16)));
                float ii = sigm(pi), ff = sigm(pf), gg = tanh_f(pg), oo = sigm(po);
                float cc = ff * cst[b][u] + ii * gg;
                cst[b][u] = cc;
                float hv = oo * tanh_f(cc);
                unsigned short hb = f2bf(hv);
                hiw |= (unsigned long long)hb << (j * 16);
                low |= (unsigned long long)f2bf(hv - bf2f(hb)) << (j * 16);
            }
            unsigned short* nh = hring + (size_t)(p & 3) * 131072;
            size_t hoff = (size_t)b * NH + u0 + (q4 << 2);
            __hip_atomic_store((unsigned long long*)(nh + hoff), hiw, __ATOMIC_RELAXED, AGT);
            __hip_atomic_store((unsigned long long*)(nh + 65536 + hoff), low, __ATOMIC_RELAXED, AGT);
            asm volatile("s_waitcnt vmcnt(0)" ::: "memory");  // h stores at coherence point
            __syncthreads();
            if (tid == 0)
                __hip_atomic_store(gfl + wg * 16, p, __ATOMIC_RELAXED, AGT);
        }
    } else {
        // ================= logit WG: vocab rows [v0, v0+64) =================
        const int lw = wg - NGATE;
        const int v0 = lw << 6;
        for (int c = tid; c < 8192; c += 256) {   // 64 rows of fc_w -> LDS
            int row = c >> 7;
            int col8 = (c & 127) << 3;
            int grow = v0 + row; if (grow > NV - 1) grow = NV - 1;
            const float* src = fcw + (size_t)grow * NH + col8;
            float4 a = *(const float4*)src;
            float4 b2 = *(const float4*)(src + 4);
            union { unsigned short us[8]; short8 s; } w;
            w.us[0] = f2bf(a.x); w.us[1] = f2bf(a.y); w.us[2] = f2bf(a.z); w.us[3] = f2bf(a.w);
            w.us[4] = f2bf(b2.x); w.us[5] = f2bf(b2.y); w.us[6] = f2bf(b2.z); w.us[7] = f2bf(b2.w);
            int byt = ((c & 127) << 4) ^ ((row & 7) << 4);
            *(short8*)(smw + (row << 10) + (byt >> 1)) = w.s;
        }
        f32x4 fbv[4];
        #pragma unroll
        for (int rt = 0; rt < 4; ++rt)
            #pragma unroll
            for (int r = 0; r < 4; ++r) {
                int v = v0 + (rt << 4) + rq + r;
                fbv[rt][r] = fcb[v < NV ? v : NV - 1];
            }
        __syncthreads();

        for (int q = 1; q <= TT; ++q) {
            if (tid < 64) {
                int* f = gfl + tid * 16;
                while (__hip_atomic_load(f, __ATOMIC_RELAXED, AGT) < q) { }
            }
            __syncthreads();
            __builtin_amdgcn_fence(__ATOMIC_ACQUIRE, "agent");
            const unsigned short* hh = hring + (size_t)(q & 3) * 131072;  // hi plane only
            f32x4 acc[4][2] = {};
            #pragma unroll
            for (int j = 0; j < 16; ++j) {
                int kb = (((kh << 4) + j) << 5) + kl8;
                short8 bh0 = *(const short8*)(hh + ((bth << 5) + ml) * NH + kb);
                short8 bh1 = *(const short8*)(hh + ((bth << 5) + 16 + ml) * NH + kb);
                #pragma unroll
                for (int rt = 0; rt < 4; ++rt) {
                    int row = (rt << 4) + ml;
                    int byt = (kb << 1) ^ ((row & 7) << 4);
                    short8 a = *(const short8*)(smw + (row << 10) + (byt >> 1));
                    acc[rt][0] = __builtin_amdgcn_mfma_f32_16x16x32_bf16(a, bh0, acc[rt][0], 0, 0, 0);
                    acc[rt][1] = __builtin_amdgcn_mfma_f32_16x16x32_bf16(a, bh1, acc[rt][1], 0, 0, 0);
                }
            }
            if (kh) {
                #pragma unroll
                for (int rt = 0; rt < 4; ++rt)
                    #pragma unroll
                    for (int i = 0; i < 2; ++i)
                        #pragma unroll
                        for (int r = 0; r < 4; ++r)
                            gl[rt][rq + r][(bth << 5) + (i << 4) + ml] = acc[rt][i][r];
            }
            __syncthreads();
            if (!kh) {
                #pragma unroll
                for (int rt = 0; rt < 4; ++rt) {
                    int vq = v0 + (rt << 4) + rq;
                    #pragma unroll
                    for (int i = 0; i < 2; ++i) {
                        int bb = (bth << 5) + (i << 4) + ml;
                        f32x4 v = acc[rt][i] + fbv[rt];
                        #pragma unroll
                        for (int r = 0; r < 4; ++r) v[r] += gl[rt][rq + r][bb];
                        if (vq + 3 < NV) {
                            // sc1 write-through stores: never dirty-in-L2 (inv-safe)
                            union { f32x4 v; unsigned long long u[2]; } cv; cv.v = v;
                            unsigned long long* po =
                                (unsigned long long*)(out + ((size_t)bb * TT + (q - 1)) * NV + vq);
                            __hip_atomic_store(po, cv.u[0], __ATOMIC_RELAXED, AGT);
                            __hip_atomic_store(po + 1, cv.u[1], __ATOMIC_RELAXED, AGT);
                        }
                    }
                }
            }
            asm volatile("s_waitcnt vmcnt(0)" ::: "memory");  // h reads + out stores drained
            __syncthreads();
            if (tid == 0)
                __hip_atomic_store(lfl + lw * 16, q, __ATOMIC_RELAXED, AGT);
        }
    }
}

extern "C" void kernel_launch(void* const* d_in, const int* in_sizes, int n_in,
                              void* d_out, int out_size, void* d_ws, size_t ws_size,
                              hipStream_t stream) {
    const float* enc_h = (const float*)d_in[0];
    const float* enc_c = (const float*)d_in[1];
    const int* trg = (const int*)d_in[2];
    const float* Ww = (const float*)d_in[3];
    const float* Wb = (const float*)d_in[4];
    const float* fcw = (const float*)d_in[5];
    const float* fcb = (const float*)d_in[6];

    unsigned short* embT = (unsigned short*)d_ws;            // 1000 x 4096 bf16 (8 MB)
    unsigned short* hring = embT + (size_t)1000 * 4096;      // 4 bufs x [2][64][1024] bf16 (1 MB)
    int* syn = (int*)(hring + (size_t)4 * 131072);           // 64 gate flags + 16 logit flags
    float* out = (float*)d_out;

    hipMemsetAsync(syn, 0, 8192, stream);
    hipLaunchKernelGGL(embT_kernel, dim3(1024), dim3(256), 0, stream, Ww, embT);
    hipLaunchKernelGGL(h0_kernel, dim3(256), dim3(256), 0, stream, enc_h, hring);
    hipLaunchKernelGGL(lstm_kernel, dim3(NGATE + NLOGIT), dim3(256), 0, stream,
                       enc_c, trg, Ww, Wb, fcw, fcb, embT, hring, syn, out);
}

// Round 6
// 3298.886 us; speedup vs baseline: 4.2489x; 1.0452x over previous
//
#include <hip/hip_runtime.h>

// Persistent LSTM decoder, fence-lite cross-WG pipeline (ws-size-adaptive).
// 64 gate WGs (16 hidden units x 4 gates) + 16 logit WGs (64 vocab rows).
// h exchanged hi/lo-bf16 via sc1 write-through stores (vmcnt(0)-acked before flag);
// consumers use PLAIN cached loads on a RING-deep slot ring, with a wave0-only
// agent acquire fence every FCAD steps. Safety: FCAD <= RING - GUARD + 1
// (fence is ordered after observing gfl/lfl, so every stale cacher of the
// reused address happened-before the buffer_inv). Flags are packed 4B ints.
// Logit WGs release the ring slot as soon as h is consumed (before out stores).

#define TT 256
#define NH 1024
#define NV 1000
#define WROW 2024   // V + H
#define NGATE 64
#define NLOGIT 16

typedef __attribute__((ext_vector_type(8))) short short8;
typedef __attribute__((ext_vector_type(4))) float f32x4;

#define AGT __HIP_MEMORY_SCOPE_AGENT

__device__ __forceinline__ unsigned short f2bf(float f) {
    unsigned int u = __float_as_uint(f);
    u += 0x7fffu + ((u >> 16) & 1u);
    return (unsigned short)(u >> 16);
}
__device__ __forceinline__ float bf2f(unsigned short s) {
    return __uint_as_float(((unsigned int)s) << 16);
}
__device__ __forceinline__ float sigm(float x) {
    return __builtin_amdgcn_rcpf(1.0f + __expf(-x));
}
__device__ __forceinline__ float tanh_f(float x) {
    return 2.0f * __builtin_amdgcn_rcpf(1.0f + __expf(-2.0f * x)) - 1.0f;
}

// ---- one-time: transpose-cast embedding block Ww[:, :V] -> embT[V][4096] bf16
__global__ void embT_kernel(const float* __restrict__ Ww, unsigned short* __restrict__ embT) {
    __shared__ unsigned short tile[64][80];
    const int rt = blockIdx.x & 63, vt = blockIdx.x >> 6;
    const int r0 = rt * 64, v0 = vt * 64;
    const int t = threadIdx.x;
    {
        int rr = t >> 2, c0 = (t & 3) * 16;
        for (int j = 0; j < 16; ++j) {
            int v = v0 + c0 + j;
            float x = (v < NV) ? Ww[(size_t)(r0 + rr) * WROW + v] : 0.f;
            tile[c0 + j][rr] = f2bf(x);
        }
    }
    __syncthreads();
    {
        int vv = t >> 2, k0 = (t & 3) * 16;
        int v = v0 + vv;
        if (v < NV)
            for (int j = 0; j < 16; ++j)
                embT[(size_t)v * 4096 + r0 + k0 + j] = tile[vv][k0 + j];
    }
}

// ---- one-time: split enc_h into hi/lo bf16 planes of ring slot 0
__global__ void h0_kernel(const float* __restrict__ enc_h, unsigned short* __restrict__ hring) {
    int i = blockIdx.x * 256 + threadIdx.x;  // 0..65535
    float v = enc_h[i];
    unsigned short hi = f2bf(v);
    hring[i] = hi;
    hring[65536 + i] = f2bf(v - bf2f(hi));
}

template <int RING, int GUARD, int FCAD>
__global__ void __launch_bounds__(256, 1)
lstm_kernel(const float* __restrict__ enc_c,
            const int* __restrict__ trg,
            const float* __restrict__ Ww,
            const float* __restrict__ Wb,
            const float* __restrict__ fcw,
            const float* __restrict__ fcb,
            const unsigned short* __restrict__ embT,
            unsigned short* __restrict__ hring,
            int* __restrict__ syn,
            float* __restrict__ out) {
    __shared__ unsigned short smw[65536];   // 128 KB: weight slice, XOR-swizzled rows
    __shared__ float gl[4][16][68];         // pre-acts [rowtile][row-in-tile][col 0..63]
    __shared__ float cst[64][17];           // cell state fp32 [batch][unit]

    const int wg = blockIdx.x;
    const int tid = threadIdx.x;
    const int lane = tid & 63;
    const int wv = tid >> 6;
    const int kh = wv >> 1;       // k-half (0: kt 0..15, 1: kt 16..31)
    const int bth = wv & 1;       // batch half (2 MFMA col-tiles each)
    const int ml = lane & 15;
    const int kq = lane >> 4;
    const int kl8 = kq * 8;
    const int rq = kq * 4;
    int* gfl4 = syn;              // 64 gate epoch flags, PACKED 4B (4 lines)
    int* lfl4 = syn + 64;         // 16 logit progress flags, PACKED 4B (1 line)

    if (wg < NGATE) {
        // ================= gate WG: hidden units [u0, u0+16), 4 gates =================
        const int u0 = wg * 16;
        for (int c = tid; c < 8192; c += 256) {   // 64 rows x 1024 bf16 -> LDS
            int row = c >> 7;
            int col8 = (c & 127) << 3;
            int grow = ((row >> 4) << 10) + u0 + (row & 15);   // q*1024 + u0 + uu
            const float* src = Ww + (size_t)grow * WROW + 1000 + col8;
            float4 a = *(const float4*)src;
            float4 b2 = *(const float4*)(src + 4);
            union { unsigned short us[8]; short8 s; } w;
            w.us[0] = f2bf(a.x); w.us[1] = f2bf(a.y); w.us[2] = f2bf(a.z); w.us[3] = f2bf(a.w);
            w.us[4] = f2bf(b2.x); w.us[5] = f2bf(b2.y); w.us[6] = f2bf(b2.z); w.us[7] = f2bf(b2.w);
            int byt = ((c & 127) << 4) ^ ((row & 7) << 4);
            *(short8*)(smw + (row << 10) + (byt >> 1)) = w.s;
        }
        const int b = tid & 63;       // pointwise role: batch
        const int q4 = tid >> 6;      // pointwise role: unit quad
        float bs[4][4];
        #pragma unroll
        for (int q = 0; q < 4; ++q)
            #pragma unroll
            for (int j = 0; j < 4; ++j)
                bs[q][j] = Wb[(q << 10) + u0 + (q4 << 2) + j];
        #pragma unroll
        for (int j = 0; j < 4; ++j)
            cst[b][(q4 << 2) + j] = enc_c[(size_t)b * NH + u0 + (q4 << 2) + j];
        __syncthreads();

        for (int p = 1; p <= TT; ++p) {
            // embedding prefetch (plain cached loads; overlap the spin)
            int idx = trg[b * TT + p - 1];
            unsigned long long emb[4];
            #pragma unroll
            for (int q = 0; q < 4; ++q)
                emb[q] = *(const unsigned long long*)(embT + (size_t)idx * 4096 + (q << 10) + u0 + (q4 << 2));
            // wait: wave 0 only, packed-flag polls (coalesced sc1 loads, no RMW)
            if (tid < 64) {
                if (p > 1)
                    while (__hip_atomic_load(gfl4 + tid, __ATOMIC_RELAXED, AGT) < p - 1) { }
                if (p > GUARD && tid < NLOGIT)   // ring-reuse guard vs trailing logits
                    while (__hip_atomic_load(lfl4 + tid, __ATOMIC_RELAXED, AGT) < p - GUARD) { }
                if (FCAD == 1 || (p & (FCAD - 1)) == 1)  // staleness-bounding acquire
                    __builtin_amdgcn_fence(__ATOMIC_ACQUIRE, "agent");
            }
            __syncthreads();

            const unsigned short* hh = hring + (size_t)((p - 1) & (RING - 1)) * 131072;
            const unsigned short* hl = hh + 65536;
            f32x4 acc[4][2] = {};
            #pragma unroll
            for (int j = 0; j < 16; ++j) {
                int kb = (((kh << 4) + j) << 5) + kl8;
                short8 bh0 = *(const short8*)(hh + ((bth << 5) + ml) * NH + kb);
                short8 bl0 = *(const short8*)(hl + ((bth << 5) + ml) * NH + kb);
                short8 bh1 = *(const short8*)(hh + ((bth << 5) + 16 + ml) * NH + kb);
                short8 bl1 = *(const short8*)(hl + ((bth << 5) + 16 + ml) * NH + kb);
                #pragma unroll
                for (int rt = 0; rt < 4; ++rt) {
                    int row = (rt << 4) + ml;
                    int byt = (kb << 1) ^ ((row & 7) << 4);
                    short8 a = *(const short8*)(smw + (row << 10) + (byt >> 1));
                    acc[rt][0] = __builtin_amdgcn_mfma_f32_16x16x32_bf16(a, bh0, acc[rt][0], 0, 0, 0);
                    acc[rt][0] = __builtin_amdgcn_mfma_f32_16x16x32_bf16(a, bl0, acc[rt][0], 0, 0, 0);
                    acc[rt][1] = __builtin_amdgcn_mfma_f32_16x16x32_bf16(a, bh1, acc[rt][1], 0, 0, 0);
                    acc[rt][1] = __builtin_amdgcn_mfma_f32_16x16x32_bf16(a, bl1, acc[rt][1], 0, 0, 0);
                }
            }
            // combine the two k-halves through gl
            if (kh) {
                #pragma unroll
                for (int rt = 0; rt < 4; ++rt)
                    #pragma unroll
                    for (int i = 0; i < 2; ++i)
                        #pragma unroll
                        for (int r = 0; r < 4; ++r)
                            gl[rt][rq + r][(bth << 5) + (i << 4) + ml] = acc[rt][i][r];
            }
            __syncthreads();
            if (!kh) {
                #pragma unroll
                for (int rt = 0; rt < 4; ++rt)
                    #pragma unroll
                    for (int i = 0; i < 2; ++i)
                        #pragma unroll
                        for (int r = 0; r < 4; ++r)
                            gl[rt][rq + r][(bth << 5) + (i << 4) + ml] += acc[rt][i][r];
            }
            __syncthreads();
            // pointwise: thread handles batch b, units q4*4..+3
            unsigned long long hiw = 0, low = 0;
            #pragma unroll
            for (int j = 0; j < 4; ++j) {
                int u = (q4 << 2) + j;
                float pi = gl[0][u][b] + bs[0][j] + bf2f((unsigned short)(emb[0] >> (j * 16)));
                float pf = gl[1][u][b] + bs[1][j] + bf2f((unsigned short)(emb[1] >> (j * 16)));
                float pg = gl[2][u][b] + bs[2][j] + bf2f((unsigned short)(emb[2] >> (j * 16)));
                float po = gl[3][u][b] + bs[3][j] + bf2f((unsigned short)(emb[3] >> (j * 16)));
                float ii = sigm(pi), ff = sigm(pf), gg = tanh_f(pg), oo = sigm(po);
                float cc = ff * cst[b][u] + ii * gg;
                cst[b][u] = cc;
                float hv = oo * tanh_f(cc);
                unsigned short hb = f2bf(hv);
                hiw |= (unsigned long long)hb << (j * 16);
                low |= (unsigned long long)f2bf(hv - bf2f(hb)) << (j * 16);
            }
            unsigned short* nh = hring + (size_t)(p & (RING - 1)) * 131072;
            size_t hoff = (size_t)b * NH + u0 + (q4 << 2);
            __hip_atomic_store((unsigned long long*)(nh + hoff), hiw, __ATOMIC_RELAXED, AGT);
            __hip_atomic_store((unsigned long long*)(nh + 65536 + hoff), low, __ATOMIC_RELAXED, AGT);
            asm volatile("s_waitcnt vmcnt(0)" ::: "memory");  // h stores at coherence point
            __syncthreads();
            if (tid == 0)
                __hip_atomic_store(gfl4 + wg, p, __ATOMIC_RELAXED, AGT);
        }
    } else {
        // ================= logit WG: vocab rows [v0, v0+64) =================
        const int lw = wg - NGATE;
        const int v0 = lw << 6;
        for (int c = tid; c < 8192; c += 256) {   // 64 rows of fc_w -> LDS
            int row = c >> 7;
            int col8 = (c & 127) << 3;
            int grow = v0 + row; if (grow > NV - 1) grow = NV - 1;
            const float* src = fcw + (size_t)grow * NH + col8;
            float4 a = *(const float4*)src;
            float4 b2 = *(const float4*)(src + 4);
            union { unsigned short us[8]; short8 s; } w;
            w.us[0] = f2bf(a.x); w.us[1] = f2bf(a.y); w.us[2] = f2bf(a.z); w.us[3] = f2bf(a.w);
            w.us[4] = f2bf(b2.x); w.us[5] = f2bf(b2.y); w.us[6] = f2bf(b2.z); w.us[7] = f2bf(b2.w);
            int byt = ((c & 127) << 4) ^ ((row & 7) << 4);
            *(short8*)(smw + (row << 10) + (byt >> 1)) = w.s;
        }
        f32x4 fbv[4];
        #pragma unroll
        for (int rt = 0; rt < 4; ++rt)
            #pragma unroll
            for (int r = 0; r < 4; ++r) {
                int v = v0 + (rt << 4) + rq + r;
                fbv[rt][r] = fcb[v < NV ? v : NV - 1];
            }
        __syncthreads();

        for (int q = 1; q <= TT; ++q) {
            if (tid < 64) {
                while (__hip_atomic_load(gfl4 + tid, __ATOMIC_RELAXED, AGT) < q) { }
                if (FCAD == 1 || (q & (FCAD - 1)) == 1)
                    __builtin_amdgcn_fence(__ATOMIC_ACQUIRE, "agent");
            }
            __syncthreads();
            const unsigned short* hh = hring + (size_t)(q & (RING - 1)) * 131072;  // hi plane
            f32x4 acc[4][2] = {};
            #pragma unroll
            for (int j = 0; j < 16; ++j) {
                int kb = (((kh << 4) + j) << 5) + kl8;
                short8 bh0 = *(const short8*)(hh + ((bth << 5) + ml) * NH + kb);
                short8 bh1 = *(const short8*)(hh + ((bth << 5) + 16 + ml) * NH + kb);
                #pragma unroll
                for (int rt = 0; rt < 4; ++rt) {
                    int row = (rt << 4) + ml;
                    int byt = (kb << 1) ^ ((row & 7) << 4);
                    short8 a = *(const short8*)(smw + (row << 10) + (byt >> 1));
                    acc[rt][0] = __builtin_amdgcn_mfma_f32_16x16x32_bf16(a, bh0, acc[rt][0], 0, 0, 0);
                    acc[rt][1] = __builtin_amdgcn_mfma_f32_16x16x32_bf16(a, bh1, acc[rt][1], 0, 0, 0);
                }
            }
            if (kh) {
                #pragma unroll
                for (int rt = 0; rt < 4; ++rt)
                    #pragma unroll
                    for (int i = 0; i < 2; ++i)
                        #pragma unroll
                        for (int r = 0; r < 4; ++r)
                            gl[rt][rq + r][(bth << 5) + (i << 4) + ml] = acc[rt][i][r];
            }
            __syncthreads();
            // h fully consumed (data-dep through MFMAs + barrier): release slot NOW,
            // before the out stores -> HBM ack latency leaves the critical path.
            if (tid == 0)
                __hip_atomic_store(lfl4 + lw, q, __ATOMIC_RELAXED, AGT);
            if (!kh) {
                #pragma unroll
                for (int rt = 0; rt < 4; ++rt) {
                    int vq = v0 + (rt << 4) + rq;
                    #pragma unroll
                    for (int i = 0; i < 2; ++i) {
                        int bb = (bth << 5) + (i << 4) + ml;
                        f32x4 v = acc[rt][i] + fbv[rt];
                        #pragma unroll
                        for (int r = 0; r < 4; ++r) v[r] += gl[rt][rq + r][bb];
                        if (vq + 3 < NV) {
                            // sc1 write-through stores: never dirty-in-L2 (inv-safe)
                            union { f32x4 v; unsigned long long u[2]; } cv; cv.v = v;
                            unsigned long long* po =
                                (unsigned long long*)(out + ((size_t)bb * TT + (q - 1)) * NV + vq);
                            __hip_atomic_store(po, cv.u[0], __ATOMIC_RELAXED, AGT);
                            __hip_atomic_store(po + 1, cv.u[1], __ATOMIC_RELAXED, AGT);
                        }
                    }
                }
            }
            __syncthreads();   // gl reuse guard for next iteration (no vmcnt drain)
        }
    }
}

extern "C" void kernel_launch(void* const* d_in, const int* in_sizes, int n_in,
                              void* d_out, int out_size, void* d_ws, size_t ws_size,
                              hipStream_t stream) {
    const float* enc_h = (const float*)d_in[0];
    const float* enc_c = (const float*)d_in[1];
    const int* trg = (const int*)d_in[2];
    const float* Ww = (const float*)d_in[3];
    const float* Wb = (const float*)d_in[4];
    const float* fcw = (const float*)d_in[5];
    const float* fcb = (const float*)d_in[6];
    float* out = (float*)d_out;

    unsigned short* embT = (unsigned short*)d_ws;        // 1000 x 4096 bf16 (8 MB)
    unsigned short* hring = embT + (size_t)1000 * 4096;  // RING slots x 256 KB

    const size_t embBytes = (size_t)1000 * 4096 * 2;
    const size_t slotBytes = (size_t)131072 * 2;
    const size_t need16 = embBytes + 16 * slotBytes + 8192;  // 12.01 MB

    hipLaunchKernelGGL(embT_kernel, dim3(1024), dim3(256), 0, stream, Ww, embT);
    hipLaunchKernelGGL(h0_kernel, dim3(256), dim3(256), 0, stream, enc_h, hring);

    if (ws_size >= need16) {
        int* syn = (int*)(hring + (size_t)16 * 131072);
        hipMemsetAsync(syn, 0, 8192, stream);
        lstm_kernel<16, 8, 8><<<dim3(NGATE + NLOGIT), dim3(256), 0, stream>>>(
            enc_c, trg, Ww, Wb, fcw, fcb, embT, hring, syn, out);
    } else {
        int* syn = (int*)(hring + (size_t)4 * 131072);
        hipMemsetAsync(syn, 0, 8192, stream);
        lstm_kernel<4, 4, 1><<<dim3(NGATE + NLOGIT), dim3(256), 0, stream>>>(
            enc_c, trg, Ww, Wb, fcw, fcb, embT, hring, syn, out);
    }
}

// Round 7
// 2234.363 us; speedup vs baseline: 6.2732x; 1.4764x over previous
//
#include <hip/hip_runtime.h>

// Persistent LSTM decoder, fence-lite cross-WG pipeline, fp16 datapath.
// 64 gate WGs (16 hidden units x 4 gates) + 16 logit WGs (64 vocab rows).
// h exchanged as a SINGLE fp16 plane via sc1 write-through stores
// (vmcnt(0)-acked before flag); consumers use PLAIN cached loads on a
// RING-deep slot ring, with a wave0-only agent acquire fence every FCAD steps.
// Safety: FCAD <= RING - GUARD + 1. Weights fp16 in LDS (XOR-swizzled).
// Cell state lives in registers (static thread mapping). Flags packed 4B.

#define TT 256
#define NH 1024
#define NV 1000
#define WROW 2024   // V + H
#define NGATE 64
#define NLOGIT 16

typedef __attribute__((ext_vector_type(8))) short short8;
typedef __attribute__((ext_vector_type(8))) _Float16 half8;
typedef __attribute__((ext_vector_type(4))) float f32x4;

#define AGT __HIP_MEMORY_SCOPE_AGENT

__device__ __forceinline__ unsigned short f2bf(float f) {
    unsigned int u = __float_as_uint(f);
    u += 0x7fffu + ((u >> 16) & 1u);
    return (unsigned short)(u >> 16);
}
__device__ __forceinline__ float bf2f(unsigned short s) {
    return __uint_as_float(((unsigned int)s) << 16);
}
__device__ __forceinline__ unsigned short f2h(float f) {
    return __builtin_bit_cast(unsigned short, (_Float16)f);
}
__device__ __forceinline__ half8 as_h8(short8 s) {
    return __builtin_bit_cast(half8, s);
}
__device__ __forceinline__ float sigm(float x) {
    return __builtin_amdgcn_rcpf(1.0f + __expf(-x));
}
__device__ __forceinline__ float tanh_f(float x) {
    return 2.0f * __builtin_amdgcn_rcpf(1.0f + __expf(-2.0f * x)) - 1.0f;
}

// ---- one-time: transpose-cast embedding block Ww[:, :V] -> embT[V][4096] bf16
__global__ void embT_kernel(const float* __restrict__ Ww, unsigned short* __restrict__ embT) {
    __shared__ unsigned short tile[64][80];
    const int rt = blockIdx.x & 63, vt = blockIdx.x >> 6;
    const int r0 = rt * 64, v0 = vt * 64;
    const int t = threadIdx.x;
    {
        int rr = t >> 2, c0 = (t & 3) * 16;
        for (int j = 0; j < 16; ++j) {
            int v = v0 + c0 + j;
            float x = (v < NV) ? Ww[(size_t)(r0 + rr) * WROW + v] : 0.f;
            tile[c0 + j][rr] = f2bf(x);
        }
    }
    __syncthreads();
    {
        int vv = t >> 2, k0 = (t & 3) * 16;
        int v = v0 + vv;
        if (v < NV)
            for (int j = 0; j < 16; ++j)
                embT[(size_t)v * 4096 + r0 + k0 + j] = tile[vv][k0 + j];
    }
}

// ---- one-time: enc_h -> fp16 plane of ring slot 0
__global__ void h0_kernel(const float* __restrict__ enc_h, unsigned short* __restrict__ hring) {
    int i = blockIdx.x * 256 + threadIdx.x;  // 0..65535
    hring[i] = f2h(enc_h[i]);
}

template <int RING, int GUARD, int FCAD>
__global__ void __launch_bounds__(256, 1)
lstm_kernel(const float* __restrict__ enc_c,
            const int* __restrict__ trg,
            const float* __restrict__ Ww,
            const float* __restrict__ Wb,
            const float* __restrict__ fcw,
            const float* __restrict__ fcb,
            const unsigned short* __restrict__ embT,
            unsigned short* __restrict__ hring,
            int* __restrict__ syn,
            float* __restrict__ out) {
    __shared__ unsigned short smw[65536];   // 128 KB: fp16 weight slice, XOR-swizzled
    __shared__ float gl[4][16][68];         // pre-acts [rowtile][row-in-tile][col 0..63]

    const int wg = blockIdx.x;
    const int tid = threadIdx.x;
    const int wv = tid >> 6;
    const int lane = tid & 63;
    const int kh = wv >> 1;       // k-half (0: kt 0..15, 1: kt 16..31)
    const int bth = wv & 1;       // batch half (2 MFMA col-tiles each)
    const int ml = lane & 15;
    const int kq = lane >> 4;
    const int kl8 = kq * 8;
    const int rq = kq * 4;
    int* gfl4 = syn;              // 64 gate epoch flags, PACKED 4B (4 lines)
    int* lfl4 = syn + 64;         // 16 logit progress flags, PACKED 4B (1 line)

    if (wg < NGATE) {
        // ================= gate WG: hidden units [u0, u0+16), 4 gates =================
        const int u0 = wg * 16;
        for (int c = tid; c < 8192; c += 256) {   // 64 rows x 1024 fp16 -> LDS
            int row = c >> 7;
            int col8 = (c & 127) << 3;
            int grow = ((row >> 4) << 10) + u0 + (row & 15);   // q*1024 + u0 + uu
            const float* src = Ww + (size_t)grow * WROW + 1000 + col8;
            float4 a = *(const float4*)src;
            float4 b2 = *(const float4*)(src + 4);
            union { unsigned short us[8]; short8 s; } w;
            w.us[0] = f2h(a.x); w.us[1] = f2h(a.y); w.us[2] = f2h(a.z); w.us[3] = f2h(a.w);
            w.us[4] = f2h(b2.x); w.us[5] = f2h(b2.y); w.us[6] = f2h(b2.z); w.us[7] = f2h(b2.w);
            int byt = ((c & 127) << 4) ^ ((row & 7) << 4);
            *(short8*)(smw + (row << 10) + (byt >> 1)) = w.s;
        }
        const int b = tid & 63;       // pointwise role: batch
        const int q4 = tid >> 6;      // pointwise role: unit quad
        float bs[4][4];
        #pragma unroll
        for (int q = 0; q < 4; ++q)
            #pragma unroll
            for (int j = 0; j < 4; ++j)
                bs[q][j] = Wb[(q << 10) + u0 + (q4 << 2) + j];
        float creg[4];                // cell state fp32, REGISTER-resident
        #pragma unroll
        for (int j = 0; j < 4; ++j)
            creg[j] = enc_c[(size_t)b * NH + u0 + (q4 << 2) + j];
        __syncthreads();

        for (int p = 1; p <= TT; ++p) {
            // embedding prefetch (plain cached loads; overlap the spin)
            int idx = trg[b * TT + p - 1];
            unsigned long long emb[4];
            #pragma unroll
            for (int q = 0; q < 4; ++q)
                emb[q] = *(const unsigned long long*)(embT + (size_t)idx * 4096 + (q << 10) + u0 + (q4 << 2));
            // wait: wave 0 only, packed-flag polls (coalesced sc1 loads, no RMW)
            if (tid < 64) {
                if (p > 1)
                    while (__hip_atomic_load(gfl4 + tid, __ATOMIC_RELAXED, AGT) < p - 1) { }
                if (p > GUARD && tid < NLOGIT)   // ring-reuse guard vs trailing logits
                    while (__hip_atomic_load(lfl4 + tid, __ATOMIC_RELAXED, AGT) < p - GUARD) { }
                if (FCAD == 1 || (p & (FCAD - 1)) == 1)  // staleness-bounding acquire
                    __builtin_amdgcn_fence(__ATOMIC_ACQUIRE, "agent");
            }
            __syncthreads();

            const unsigned short* hh = hring + (size_t)((p - 1) & (RING - 1)) * 65536;
            f32x4 acc[4][2] = {};
            #pragma unroll
            for (int j = 0; j < 16; ++j) {
                int kb = (((kh << 4) + j) << 5) + kl8;
                half8 bh0 = as_h8(*(const short8*)(hh + ((bth << 5) + ml) * NH + kb));
                half8 bh1 = as_h8(*(const short8*)(hh + ((bth << 5) + 16 + ml) * NH + kb));
                #pragma unroll
                for (int rt = 0; rt < 4; ++rt) {
                    int row = (rt << 4) + ml;
                    int byt = (kb << 1) ^ ((row & 7) << 4);
                    half8 a = as_h8(*(const short8*)(smw + (row << 10) + (byt >> 1)));
                    acc[rt][0] = __builtin_amdgcn_mfma_f32_16x16x32_f16(a, bh0, acc[rt][0], 0, 0, 0);
                    acc[rt][1] = __builtin_amdgcn_mfma_f32_16x16x32_f16(a, bh1, acc[rt][1], 0, 0, 0);
                }
            }
            // combine the two k-halves through gl
            if (kh) {
                #pragma unroll
                for (int rt = 0; rt < 4; ++rt)
                    #pragma unroll
                    for (int i = 0; i < 2; ++i)
                        #pragma unroll
                        for (int r = 0; r < 4; ++r)
                            gl[rt][rq + r][(bth << 5) + (i << 4) + ml] = acc[rt][i][r];
            }
            __syncthreads();
            if (!kh) {
                #pragma unroll
                for (int rt = 0; rt < 4; ++rt)
                    #pragma unroll
                    for (int i = 0; i < 2; ++i)
                        #pragma unroll
                        for (int r = 0; r < 4; ++r)
                            gl[rt][rq + r][(bth << 5) + (i << 4) + ml] += acc[rt][i][r];
            }
            __syncthreads();
            // pointwise: thread handles batch b, units q4*4..+3
            unsigned long long hw = 0;
            #pragma unroll
            for (int j = 0; j < 4; ++j) {
                int u = (q4 << 2) + j;
                float pi = gl[0][u][b] + bs[0][j] + bf2f((unsigned short)(emb[0] >> (j * 16)));
                float pf = gl[1][u][b] + bs[1][j] + bf2f((unsigned short)(emb[1] >> (j * 16)));
                float pg = gl[2][u][b] + bs[2][j] + bf2f((unsigned short)(emb[2] >> (j * 16)));
                float po = gl[3][u][b] + bs[3][j] + bf2f((unsigned short)(emb[3] >> (j * 16)));
                float ii = sigm(pi), ff = sigm(pf), gg = tanh_f(pg), oo = sigm(po);
                float cc = ff * creg[j] + ii * gg;
                creg[j] = cc;
                float hv = oo * tanh_f(cc);
                hw |= (unsigned long long)f2h(hv) << (j * 16);
            }
            unsigned short* nh = hring + (size_t)(p & (RING - 1)) * 65536;
            __hip_atomic_store((unsigned long long*)(nh + (size_t)b * NH + u0 + (q4 << 2)),
                               hw, __ATOMIC_RELAXED, AGT);
            asm volatile("s_waitcnt vmcnt(0)" ::: "memory");  // h store at coherence point
            __syncthreads();
            if (tid == 0)
                __hip_atomic_store(gfl4 + wg, p, __ATOMIC_RELAXED, AGT);
        }
    } else {
        // ================= logit WG: vocab rows [v0, v0+64) =================
        const int lw = wg - NGATE;
        const int v0 = lw << 6;
        for (int c = tid; c < 8192; c += 256) {   // 64 rows of fc_w (fp16) -> LDS
            int row = c >> 7;
            int col8 = (c & 127) << 3;
            int grow = v0 + row; if (grow > NV - 1) grow = NV - 1;
            const float* src = fcw + (size_t)grow * NH + col8;
            float4 a = *(const float4*)src;
            float4 b2 = *(const float4*)(src + 4);
            union { unsigned short us[8]; short8 s; } w;
            w.us[0] = f2h(a.x); w.us[1] = f2h(a.y); w.us[2] = f2h(a.z); w.us[3] = f2h(a.w);
            w.us[4] = f2h(b2.x); w.us[5] = f2h(b2.y); w.us[6] = f2h(b2.z); w.us[7] = f2h(b2.w);
            int byt = ((c & 127) << 4) ^ ((row & 7) << 4);
            *(short8*)(smw + (row << 10) + (byt >> 1)) = w.s;
        }
        f32x4 fbv[4];
        #pragma unroll
        for (int rt = 0; rt < 4; ++rt)
            #pragma unroll
            for (int r = 0; r < 4; ++r) {
                int v = v0 + (rt << 4) + rq + r;
                fbv[rt][r] = fcb[v < NV ? v : NV - 1];
            }
        __syncthreads();

        for (int q = 1; q <= TT; ++q) {
            if (tid < 64) {
                while (__hip_atomic_load(gfl4 + tid, __ATOMIC_RELAXED, AGT) < q) { }
                if (FCAD == 1 || (q & (FCAD - 1)) == 1)
                    __builtin_amdgcn_fence(__ATOMIC_ACQUIRE, "agent");
            }
            __syncthreads();
            const unsigned short* hh = hring + (size_t)(q & (RING - 1)) * 65536;
            f32x4 acc[4][2] = {};
            #pragma unroll
            for (int j = 0; j < 16; ++j) {
                int kb = (((kh << 4) + j) << 5) + kl8;
                half8 bh0 = as_h8(*(const short8*)(hh + ((bth << 5) + ml) * NH + kb));
                half8 bh1 = as_h8(*(const short8*)(hh + ((bth << 5) + 16 + ml) * NH + kb));
                #pragma unroll
                for (int rt = 0; rt < 4; ++rt) {
                    int row = (rt << 4) + ml;
                    int byt = (kb << 1) ^ ((row & 7) << 4);
                    half8 a = as_h8(*(const short8*)(smw + (row << 10) + (byt >> 1)));
                    acc[rt][0] = __builtin_amdgcn_mfma_f32_16x16x32_f16(a, bh0, acc[rt][0], 0, 0, 0);
                    acc[rt][1] = __builtin_amdgcn_mfma_f32_16x16x32_f16(a, bh1, acc[rt][1], 0, 0, 0);
                }
            }
            if (kh) {
                #pragma unroll
                for (int rt = 0; rt < 4; ++rt)
                    #pragma unroll
                    for (int i = 0; i < 2; ++i)
                        #pragma unroll
                        for (int r = 0; r < 4; ++r)
                            gl[rt][rq + r][(bth << 5) + (i << 4) + ml] = acc[rt][i][r];
            }
            __syncthreads();
            // h fully consumed: release slot NOW (before the out stores)
            if (tid == 0)
                __hip_atomic_store(lfl4 + lw, q, __ATOMIC_RELAXED, AGT);
            if (!kh) {
                #pragma unroll
                for (int rt = 0; rt < 4; ++rt) {
                    int vq = v0 + (rt << 4) + rq;
                    #pragma unroll
                    for (int i = 0; i < 2; ++i) {
                        int bb = (bth << 5) + (i << 4) + ml;
                        f32x4 v = acc[rt][i] + fbv[rt];
                        #pragma unroll
                        for (int r = 0; r < 4; ++r) v[r] += gl[rt][rq + r][bb];
                        if (vq + 3 < NV) {
                            // sc1 write-through stores: never dirty-in-L2 (inv-safe)
                            union { f32x4 v; unsigned long long u[2]; } cv; cv.v = v;
                            unsigned long long* po =
                                (unsigned long long*)(out + ((size_t)bb * TT + (q - 1)) * NV + vq);
                            __hip_atomic_store(po, cv.u[0], __ATOMIC_RELAXED, AGT);
                            __hip_atomic_store(po + 1, cv.u[1], __ATOMIC_RELAXED, AGT);
                        }
                    }
                }
            }
            __syncthreads();   // gl reuse guard for next iteration (no vmcnt drain)
        }
    }
}

extern "C" void kernel_launch(void* const* d_in, const int* in_sizes, int n_in,
                              void* d_out, int out_size, void* d_ws, size_t ws_size,
                              hipStream_t stream) {
    const float* enc_h = (const float*)d_in[0];
    const float* enc_c = (const float*)d_in[1];
    const int* trg = (const int*)d_in[2];
    const float* Ww = (const float*)d_in[3];
    const float* Wb = (const float*)d_in[4];
    const float* fcw = (const float*)d_in[5];
    const float* fcb = (const float*)d_in[6];
    float* out = (float*)d_out;

    unsigned short* embT = (unsigned short*)d_ws;        // 1000 x 4096 bf16 (8 MB)
    unsigned short* hring = embT + (size_t)1000 * 4096;  // RING slots x 128 KB (fp16 plane)

    const size_t embBytes = (size_t)1000 * 4096 * 2;
    const size_t slotBytes = (size_t)65536 * 2;
    const size_t need16 = embBytes + 16 * slotBytes + 8192;  // ~10.3 MB

    hipLaunchKernelGGL(embT_kernel, dim3(1024), dim3(256), 0, stream, Ww, embT);
    hipLaunchKernelGGL(h0_kernel, dim3(256), dim3(256), 0, stream, enc_h, hring);

    if (ws_size >= need16) {
        int* syn = (int*)(hring + (size_t)16 * 65536);
        hipMemsetAsync(syn, 0, 8192, stream);
        lstm_kernel<16, 8, 8><<<dim3(NGATE + NLOGIT), dim3(256), 0, stream>>>(
            enc_c, trg, Ww, Wb, fcw, fcb, embT, hring, syn, out);
    } else {
        int* syn = (int*)(hring + (size_t)4 * 65536);
        hipMemsetAsync(syn, 0, 8192, stream);
        lstm_kernel<4, 4, 1><<<dim3(NGATE + NLOGIT), dim3(256), 0, stream>>>(
            enc_c, trg, Ww, Wb, fcw, fcb, embT, hring, syn, out);
    }
}